// Round 5
// baseline (42.431 us; speedup 1.0000x reference)
//
#include <hip/hip_runtime.h>

#define N    256
#define NH   64
#define NC   14
#define NCH  4            // k-chunks per anchor i (grid.y)
#define KPC  (N / NCH)    // 64 k's per chunk
#define SUBS 2            // k-subchunks per block (thread dim)
#define KPT  (KPC / SUBS) // 32 k's per thread
#define TPB  (N * SUBS)   // 512 threads
#define NBLK (N * NCH)    // 1024 blocks total

// Single fused kernel. Block (i, ch): threads t -> (j = t&255, sub = t>>8).
// Phase A (sub==0): ds[j] = dist_sim[i][j] (fp64 dot), dg[j] = dist_gt[i][j]
//   (exact int), LDS histogram of dg (integer atomics -> deterministic).
// Z_i and counts_i come from the histogram in CLOSED FORM (exact integers):
//   Z_ij  = 2^dj * #{k: dk<dj} - sum_{dk<dj} 2^dk
//   cnt_ij = h[dj-1] + h[dj-2]
// Phase B: inner loop over 32 k's computes only the fp64 numerator; under the
//   keep mask the weight r is one of {2^(dj-1), 3*2^(dj-2)} -> branchless select.
// Finalize: last block (device-scope atomic counter) folds the 1024 partials
//   in fixed order and writes the scalar.
__global__ __launch_bounds__(TPB) void osml_fused(
    const float* __restrict__ H,     // hash_features [N][NH]
    const float* __restrict__ L,     // labels        [N][NC]
    double*       __restrict__ p_num, // [N*NCH]
    long long*    __restrict__ p_z,   // [N]
    int*          __restrict__ p_cnt, // [N]
    unsigned int* __restrict__ ctr,   // zeroed by memsetAsync each call
    float*        __restrict__ out)
{
    const int i   = blockIdx.x;
    const int ch  = blockIdx.y;
    const int t   = threadIdx.x;
    const int j   = t & (N - 1);
    const int sub = t >> 8;

    __shared__ float     Hi[NH];
    __shared__ float     Li[NC];
    __shared__ double    ds[N];      // dist_sim row i (fp64); reused as loss buf in finalize
    __shared__ int       dg[N];      // dist_gt row i (exact int)
    __shared__ int       hist[16];
    __shared__ int       cntlt[16];  // #{d' < d}
    __shared__ int       sumlt[16];  // sum_{d' < d} 2^d' * h[d']
    __shared__ double    w_num[TPB / 64];
    __shared__ long long w_z[4];
    __shared__ int       w_c[4];
    __shared__ long long s_cc[N];
    __shared__ int       is_last;

    if (t < NH) Hi[t] = H[i * NH + t];
    else if (t < NH + NC) Li[t - NH] = L[i * NC + (t - NH)];
    if (t < 16) hist[t] = 0;
    __syncthreads();

    if (sub == 0) {
        // dist_sim[i][j] in fp64 (4 accumulators, float4 loads; L2-resident)
        const float4* Hj4 = (const float4*)(H + j * NH);
        double a0 = 0.0, a1 = 0.0, a2 = 0.0, a3 = 0.0;
        #pragma unroll
        for (int q = 0; q < NH / 4; ++q) {
            float4 v = Hj4[q];
            a0 += (double)Hi[4 * q + 0] * (double)v.x;
            a1 += (double)Hi[4 * q + 1] * (double)v.y;
            a2 += (double)Hi[4 * q + 2] * (double)v.z;
            a3 += (double)Hi[4 * q + 3] * (double)v.w;
        }
        ds[j] = 0.5 * ((double)NH - ((a0 + a1) + (a2 + a3)));

        // dist_gt[i][j]: 0/1 products, <=14 terms -> exact in fp32
        float dsum = 0.0f;
        #pragma unroll
        for (int c = 0; c < NC; ++c)
            dsum += Li[c] * L[j * NC + c];
        int d = (int)(dsum + 0.5f);
        if (j == i) d = 0;               // diagonal zeroed
        dg[j] = d;
        atomicAdd(&hist[d], 1);          // integer LDS atomic: order-free, exact
    }
    __syncthreads();

    if (t == 0) {
        int c = 0, s = 0;
        #pragma unroll
        for (int d = 0; d < 16; ++d) {
            cntlt[d] = c; sumlt[d] = s;
            c += hist[d]; s += hist[d] << d;   // max 256<<14 = 4.2M, fits int
        }
    }
    __syncthreads();

    const int    dj   = dg[j];
    const int    g2j  = 1 << dj;
    const double dsj5 = ds[j] + 5.0;
    const double r1   = (double)(g2j >> 1);        // weight when dk == dj-1
    const double r2   = (double)(3 * (g2j >> 2));  // weight when dk == dj-2

    // inner loop: numerator only (Z/cnt are closed-form)
    double n0 = 0.0, n1 = 0.0;
    const int k0 = ch * KPC + sub * KPT;
    #pragma unroll
    for (int kk = 0; kk < KPT; kk += 2) {
        {
            const int    dd = dj - dg[k0 + kk];
            double       w  = (dd == 1) ? r1 : ((dd == 2) ? r2 : 0.0);
            const double tt = dsj5 - ds[k0 + kk];
            w = (tt > 0.0) ? w : 0.0;
            n0 = fma(w, tt, n0);
        }
        {
            const int    dd = dj - dg[k0 + kk + 1];
            double       w  = (dd == 1) ? r1 : ((dd == 2) ? r2 : 0.0);
            const double tt = dsj5 - ds[k0 + kk + 1];
            w = (tt > 0.0) ? w : 0.0;
            n1 = fma(w, tt, n1);
        }
    }
    double num = n0 + n1;

    // fixed-order wave reduce (deterministic)
    #pragma unroll
    for (int off = 32; off > 0; off >>= 1)
        num += __shfl_down(num, off, 64);

    // exact per-(i,j) Z and keep-count, only once per anchor (ch==0, sub==0)
    long long Zj = 0; int Cj = 0;
    if (ch == 0 && sub == 0) {
        Zj = (long long)g2j * cntlt[dj] - (long long)sumlt[dj];
        Cj = (dj >= 1 ? hist[dj - 1] : 0) + (dj >= 2 ? hist[dj - 2] : 0);
    }
    #pragma unroll
    for (int off = 32; off > 0; off >>= 1) {
        Zj += __shfl_down(Zj, off, 64);
        Cj += __shfl_down(Cj, off, 64);
    }

    const int wid = t >> 6, lane = t & 63;
    if (lane == 0) {
        w_num[wid] = num;
        if (wid < 4) { w_z[wid] = Zj; w_c[wid] = Cj; }
    }
    __syncthreads();

    if (t == 0) {
        double s = ((w_num[0] + w_num[1]) + (w_num[2] + w_num[3]))
                 + ((w_num[4] + w_num[5]) + (w_num[6] + w_num[7]));
        p_num[i * NCH + ch] = s;
        if (ch == 0) {
            p_z[i]   = w_z[0] + w_z[1] + w_z[2] + w_z[3];
            p_cnt[i] = w_c[0] + w_c[1] + w_c[2] + w_c[3];
        }
        __threadfence();                       // release partials (device scope)
        unsigned int old = atomicAdd(ctr, 1u); // device-scope by default
        is_last = (old == NBLK - 1) ? 1 : 0;
    }
    __syncthreads();

    if (is_last) {
        __threadfence();                       // acquire side
        if (sub == 0) {
            double nm = 0.0;
            #pragma unroll
            for (int c = 0; c < NCH; ++c)      // fixed order
                nm += p_num[j * NCH + c];
            const long long Z = p_z[j];
            ds[j]   = (Z > 0) ? nm / (double)Z : 0.0;  // reuse ds as loss buffer
            s_cc[j] = (long long)p_cnt[j];
        }
        __syncthreads();
        for (int off = N / 2; off > 0; off >>= 1) {
            if (t < off) {
                ds[t]   += ds[t + off];
                s_cc[t] += s_cc[t + off];
            }
            __syncthreads();
        }
        if (t == 0) {
            const double    losses = ds[0];
            const long long counts = s_cc[0];
            out[0] = (float)((counts > 0) ? losses / (double)counts : losses);
        }
    }
}

extern "C" void kernel_launch(void* const* d_in, const int* in_sizes, int n_in,
                              void* d_out, int out_size, void* d_ws, size_t ws_size,
                              hipStream_t stream) {
    const float* H = (const float*)d_in[0];  // hash_features [256][64] fp32
    const float* L = (const float*)d_in[1];  // labels        [256][14] fp32
    float* out = (float*)d_out;              // scalar fp32

    double*       p_num = (double*)d_ws;                    // 1024 doubles
    long long*    p_z   = (long long*)(p_num + N * NCH);    // 256 int64
    int*          p_cnt = (int*)(p_z + N);                  // 256 int32
    unsigned int* ctr   = (unsigned int*)(p_cnt + N);       // 1 uint

    hipMemsetAsync(ctr, 0, sizeof(unsigned int), stream);   // capture-safe
    osml_fused<<<dim3(N, NCH), TPB, 0, stream>>>(H, L, p_num, p_z, p_cnt, ctr, out);
}

// Round 6
// 42.022 us; speedup vs baseline: 1.0097x; 1.0097x over previous
//
#include <hip/hip_runtime.h>

#define N    256
#define NH   64
#define NC   14
#define NCH  4            // k-chunks per anchor i (grid.y)
#define KPC  (N / NCH)    // 64 k's per chunk
#define SUBS 2            // k-subchunks per block (thread dim)
#define KPT  (KPC / SUBS) // 32 k's per thread
#define TPB  (N * SUBS)   // 512 threads
#define NBLK (N * NCH)    // 1024 blocks total

// Tiny own-kernel counter zeroing: replaces hipMemsetAsync, whose rocclr
// fillBufferAligned dispatch measured ~39 us in-graph (round-5 profile).
__global__ void zero_ctr(unsigned int* __restrict__ ctr) { *ctr = 0u; }

// Single fused kernel. Block (i, ch): threads t -> (j = t&255, sub = t>>8).
// Phase A (sub==0): ds[j] = dist_sim[i][j] (fp64 dot), dg[j] = dist_gt[i][j]
//   (exact int), LDS histogram of dg (integer atomics -> deterministic).
// Z_i and counts_i come from the histogram in CLOSED FORM (exact integers):
//   Z_ij  = 2^dj * #{k: dk<dj} - sum_{dk<dj} 2^dk
//   cnt_ij = h[dj-1] + h[dj-2]
// Phase B: inner loop over 32 k's computes only the fp64 numerator; under the
//   keep mask the weight r is one of {2^(dj-1), 3*2^(dj-2)} -> branchless select.
// Finalize: last block (device-scope atomic counter) folds the 1024 partials
//   in fixed order and writes the scalar.
__global__ __launch_bounds__(TPB) void osml_fused(
    const float* __restrict__ H,     // hash_features [N][NH]
    const float* __restrict__ L,     // labels        [N][NC]
    double*       __restrict__ p_num, // [N*NCH]
    long long*    __restrict__ p_z,   // [N]
    int*          __restrict__ p_cnt, // [N]
    unsigned int* __restrict__ ctr,   // zeroed by zero_ctr each call
    float*        __restrict__ out)
{
    const int i   = blockIdx.x;
    const int ch  = blockIdx.y;
    const int t   = threadIdx.x;
    const int j   = t & (N - 1);
    const int sub = t >> 8;

    __shared__ float     Hi[NH];
    __shared__ float     Li[NC];
    __shared__ double    ds[N];      // dist_sim row i (fp64); reused as loss buf in finalize
    __shared__ int       dg[N];      // dist_gt row i (exact int)
    __shared__ int       hist[16];
    __shared__ int       cntlt[16];  // #{d' < d}
    __shared__ int       sumlt[16];  // sum_{d' < d} 2^d' * h[d']
    __shared__ double    w_num[TPB / 64];
    __shared__ long long w_z[4];
    __shared__ int       w_c[4];
    __shared__ long long s_cc[N];
    __shared__ int       is_last;

    if (t < NH) Hi[t] = H[i * NH + t];
    else if (t < NH + NC) Li[t - NH] = L[i * NC + (t - NH)];
    if (t < 16) hist[t] = 0;
    __syncthreads();

    if (sub == 0) {
        // dist_sim[i][j] in fp64 (4 accumulators, float4 loads; L2-resident)
        const float4* Hj4 = (const float4*)(H + j * NH);
        double a0 = 0.0, a1 = 0.0, a2 = 0.0, a3 = 0.0;
        #pragma unroll
        for (int q = 0; q < NH / 4; ++q) {
            float4 v = Hj4[q];
            a0 += (double)Hi[4 * q + 0] * (double)v.x;
            a1 += (double)Hi[4 * q + 1] * (double)v.y;
            a2 += (double)Hi[4 * q + 2] * (double)v.z;
            a3 += (double)Hi[4 * q + 3] * (double)v.w;
        }
        ds[j] = 0.5 * ((double)NH - ((a0 + a1) + (a2 + a3)));

        // dist_gt[i][j]: 0/1 products, <=14 terms -> exact in fp32
        float dsum = 0.0f;
        #pragma unroll
        for (int c = 0; c < NC; ++c)
            dsum += Li[c] * L[j * NC + c];
        int d = (int)(dsum + 0.5f);
        if (j == i) d = 0;               // diagonal zeroed
        dg[j] = d;
        atomicAdd(&hist[d], 1);          // integer LDS atomic: order-free, exact
    }
    __syncthreads();

    if (t == 0) {
        int c = 0, s = 0;
        #pragma unroll
        for (int d = 0; d < 16; ++d) {
            cntlt[d] = c; sumlt[d] = s;
            c += hist[d]; s += hist[d] << d;   // max 256<<14 = 4.2M, fits int
        }
    }
    __syncthreads();

    const int    dj   = dg[j];
    const int    g2j  = 1 << dj;
    const double dsj5 = ds[j] + 5.0;
    const double r1   = (double)(g2j >> 1);        // weight when dk == dj-1
    const double r2   = (double)(3 * (g2j >> 2));  // weight when dk == dj-2

    // inner loop: numerator only (Z/cnt are closed-form)
    double n0 = 0.0, n1 = 0.0;
    const int k0 = ch * KPC + sub * KPT;
    #pragma unroll
    for (int kk = 0; kk < KPT; kk += 2) {
        {
            const int    dd = dj - dg[k0 + kk];
            double       w  = (dd == 1) ? r1 : ((dd == 2) ? r2 : 0.0);
            const double tt = dsj5 - ds[k0 + kk];
            w = (tt > 0.0) ? w : 0.0;
            n0 = fma(w, tt, n0);
        }
        {
            const int    dd = dj - dg[k0 + kk + 1];
            double       w  = (dd == 1) ? r1 : ((dd == 2) ? r2 : 0.0);
            const double tt = dsj5 - ds[k0 + kk + 1];
            w = (tt > 0.0) ? w : 0.0;
            n1 = fma(w, tt, n1);
        }
    }
    double num = n0 + n1;

    // fixed-order wave reduce (deterministic)
    #pragma unroll
    for (int off = 32; off > 0; off >>= 1)
        num += __shfl_down(num, off, 64);

    // exact per-(i,j) Z and keep-count, only once per anchor (ch==0, sub==0)
    long long Zj = 0; int Cj = 0;
    if (ch == 0 && sub == 0) {
        Zj = (long long)g2j * cntlt[dj] - (long long)sumlt[dj];
        Cj = (dj >= 1 ? hist[dj - 1] : 0) + (dj >= 2 ? hist[dj - 2] : 0);
    }
    #pragma unroll
    for (int off = 32; off > 0; off >>= 1) {
        Zj += __shfl_down(Zj, off, 64);
        Cj += __shfl_down(Cj, off, 64);
    }

    const int wid = t >> 6, lane = t & 63;
    if (lane == 0) {
        w_num[wid] = num;
        if (wid < 4) { w_z[wid] = Zj; w_c[wid] = Cj; }
    }
    __syncthreads();

    if (t == 0) {
        double s = ((w_num[0] + w_num[1]) + (w_num[2] + w_num[3]))
                 + ((w_num[4] + w_num[5]) + (w_num[6] + w_num[7]));
        p_num[i * NCH + ch] = s;
        if (ch == 0) {
            p_z[i]   = w_z[0] + w_z[1] + w_z[2] + w_z[3];
            p_cnt[i] = w_c[0] + w_c[1] + w_c[2] + w_c[3];
        }
        __threadfence();                       // release partials (device scope)
        unsigned int old = atomicAdd(ctr, 1u); // device-scope by default
        is_last = (old == NBLK - 1) ? 1 : 0;
    }
    __syncthreads();

    if (is_last) {
        __threadfence();                       // acquire side
        if (sub == 0) {
            double nm = 0.0;
            #pragma unroll
            for (int c = 0; c < NCH; ++c)      // fixed order
                nm += p_num[j * NCH + c];
            const long long Z = p_z[j];
            ds[j]   = (Z > 0) ? nm / (double)Z : 0.0;  // reuse ds as loss buffer
            s_cc[j] = (long long)p_cnt[j];
        }
        __syncthreads();
        for (int off = N / 2; off > 0; off >>= 1) {
            if (t < off) {
                ds[t]   += ds[t + off];
                s_cc[t] += s_cc[t + off];
            }
            __syncthreads();
        }
        if (t == 0) {
            const double    losses = ds[0];
            const long long counts = s_cc[0];
            out[0] = (float)((counts > 0) ? losses / (double)counts : losses);
        }
    }
}

extern "C" void kernel_launch(void* const* d_in, const int* in_sizes, int n_in,
                              void* d_out, int out_size, void* d_ws, size_t ws_size,
                              hipStream_t stream) {
    const float* H = (const float*)d_in[0];  // hash_features [256][64] fp32
    const float* L = (const float*)d_in[1];  // labels        [256][14] fp32
    float* out = (float*)d_out;              // scalar fp32

    double*       p_num = (double*)d_ws;                    // 1024 doubles
    long long*    p_z   = (long long*)(p_num + N * NCH);    // 256 int64
    int*          p_cnt = (int*)(p_z + N);                  // 256 int32
    unsigned int* ctr   = (unsigned int*)(p_cnt + N);       // 1 uint

    zero_ctr<<<1, 1, 0, stream>>>(ctr);                     // replaces 39us fill node
    osml_fused<<<dim3(N, NCH), TPB, 0, stream>>>(H, L, p_num, p_z, p_cnt, ctr, out);
}

// Round 7
// 40.248 us; speedup vs baseline: 1.0542x; 1.0441x over previous
//
#include <hip/hip_runtime.h>

#define N    256
#define NH   64
#define NC   14
#define SUBS 4            // k-range splits per anchor (thread dim)
#define TPB  (N * SUBS)   // 1024 threads/block, 16 waves
#define KPT  (N / SUBS)   // 64 k's per thread

// Kernel 1: one block per anchor i. Thread t -> (j = t&255, sub = t>>8).
// Phase 1: 4-way parallel fp64 dot for ds[j]; sub0 computes dg[j] (exact int)
//          + LDS histogram (integer atomics -> order-free, exact).
// Phase 2: closed-form per-anchor Z/cnt from the histogram (exact integers):
//            Z_ij  = 2^dj * #{k: dk<dj} - sum_{dk<dj} 2^dk
//            cnt_ij = h[dj-1] + h[dj-2]
//          Numerator-only inner loop (64 k's/thread); under the keep mask the
//          weight is one of {2^(dj-1), 3*2^(dj-2)} -> branchless select.
// All reductions fixed-order -> deterministic across graph replays.
__global__ __launch_bounds__(TPB) void osml_anchor(
    const float* __restrict__ H,      // hash_features [N][NH]
    const float* __restrict__ L,      // labels        [N][NC]
    double*    __restrict__ loss_i,   // [N]
    long long* __restrict__ cnt_i)    // [N]
{
    const int i   = blockIdx.x;
    const int t   = threadIdx.x;
    const int j   = t & (N - 1);
    const int sub = t >> 8;

    __shared__ float     Hi[NH];
    __shared__ float     Li[NC];
    __shared__ double    pd[SUBS][N];   // partial dots
    __shared__ double    ds[N];         // dist_sim row i (fp64)
    __shared__ int       dg[N];         // dist_gt row i (exact int)
    __shared__ int       hist[16];
    __shared__ int       cntlt[16];     // #{d' < d}
    __shared__ int       sumlt[16];     // sum_{d' < d} 2^d' * h[d']
    __shared__ double    w_num[TPB / 64];
    __shared__ long long w_z[TPB / 64];
    __shared__ int       w_c[TPB / 64];

    if (t < NH) Hi[t] = H[i * NH + t];
    else if (t < NH + NC) Li[t - NH] = L[i * NC + (t - NH)];
    if (t >= TPB - 16) hist[t - (TPB - 16)] = 0;   // sub3 tail zeroes hist
    __syncthreads();

    // ---- Phase 1: parallel fp64 dot (thread (j,sub) does 16 of 64 terms) ----
    {
        const float4* Hj4   = (const float4*)(H + j * NH + sub * 16);
        const float*  Hisub = Hi + sub * 16;
        double a0 = 0.0, a1 = 0.0, a2 = 0.0, a3 = 0.0;
        #pragma unroll
        for (int q = 0; q < 4; ++q) {
            float4 v = Hj4[q];
            a0 += (double)Hisub[4 * q + 0] * (double)v.x;
            a1 += (double)Hisub[4 * q + 1] * (double)v.y;
            a2 += (double)Hisub[4 * q + 2] * (double)v.z;
            a3 += (double)Hisub[4 * q + 3] * (double)v.w;
        }
        pd[sub][j] = (a0 + a1) + (a2 + a3);
    }
    if (sub == 0) {
        // dist_gt[i][j]: 0/1 products, <=14 terms -> exact in fp32
        float dsum = 0.0f;
        #pragma unroll
        for (int c = 0; c < NC; ++c)
            dsum += Li[c] * L[j * NC + c];
        int d = (int)(dsum + 0.5f);
        if (j == i) d = 0;               // diagonal zeroed
        dg[j] = d;
        atomicAdd(&hist[d], 1);          // integer LDS atomic: exact, order-free
    }
    __syncthreads();

    if (sub == 0)
        ds[j] = 0.5 * ((double)NH - ((pd[0][j] + pd[1][j]) + (pd[2][j] + pd[3][j])));
    if (t == TPB - 1) {                  // idle sub3 thread does the 15-bin scan
        int c = 0, s = 0;
        #pragma unroll
        for (int d = 0; d < 16; ++d) {
            cntlt[d] = c; sumlt[d] = s;
            c += hist[d]; s += hist[d] << d;   // max 256<<14, fits int
        }
    }
    __syncthreads();

    // ---- Phase 2: numerator-only inner loop ----
    const int    dj   = dg[j];
    const int    g2j  = 1 << dj;
    const double dsj5 = ds[j] + 5.0;
    const double r1   = (double)(g2j >> 1);        // weight when dk == dj-1
    const double r2   = (double)(3 * (g2j >> 2));  // weight when dk == dj-2

    double n0 = 0.0, n1 = 0.0, n2 = 0.0, n3 = 0.0;
    const int k0 = sub * KPT;
#define OSML_BODY(O, ACC) {                                   \
        const int    dd = dj - dg[k0 + kk + (O)];             \
        double       w  = (dd == 1) ? r1 : ((dd == 2) ? r2 : 0.0); \
        const double tt = dsj5 - ds[k0 + kk + (O)];           \
        w = (tt > 0.0) ? w : 0.0;                             \
        ACC = fma(w, tt, ACC); }
    #pragma unroll
    for (int kk = 0; kk < KPT; kk += 4) {
        OSML_BODY(0, n0)
        OSML_BODY(1, n1)
        OSML_BODY(2, n2)
        OSML_BODY(3, n3)
    }
#undef OSML_BODY
    double num = (n0 + n1) + (n2 + n3);

    // per-(i,j) exact Z and keep-count, counted once (sub==0 only)
    long long Zj = 0; int Cj = 0;
    if (sub == 0) {
        Zj = (long long)g2j * cntlt[dj] - (long long)sumlt[dj];
        Cj = (dj >= 1 ? hist[dj - 1] : 0) + (dj >= 2 ? hist[dj - 2] : 0);
    }

    // fixed-order wave reduce, then 16 wave-partials summed sequentially
    #pragma unroll
    for (int off = 32; off > 0; off >>= 1) {
        num += __shfl_down(num, off, 64);
        Zj  += __shfl_down(Zj,  off, 64);
        Cj  += __shfl_down(Cj,  off, 64);
    }
    const int wid = t >> 6, lane = t & 63;
    if (lane == 0) { w_num[wid] = num; w_z[wid] = Zj; w_c[wid] = Cj; }
    __syncthreads();

    if (t == 0) {
        double    s = 0.0;
        long long Z = 0, C = 0;
        #pragma unroll
        for (int w2 = 0; w2 < TPB / 64; ++w2) {   // fixed order
            s += w_num[w2]; Z += w_z[w2]; C += w_c[w2];
        }
        loss_i[i] = (Z > 0) ? s / (double)Z : 0.0;
        cnt_i[i]  = C;
    }
}

// Kernel 2: single block, deterministic reduction over the 256 anchors.
__global__ __launch_bounds__(N) void osml_final(
    const double*    __restrict__ loss_i,
    const long long* __restrict__ cnt_i,
    float*           __restrict__ out)
{
    const int t = threadIdx.x;
    double    l = loss_i[t];
    long long c = cnt_i[t];
    #pragma unroll
    for (int off = 32; off > 0; off >>= 1) {
        l += __shfl_down(l, off, 64);
        c += __shfl_down(c, off, 64);
    }
    __shared__ double    sl[4];
    __shared__ long long sc[4];
    if ((t & 63) == 0) { sl[t >> 6] = l; sc[t >> 6] = c; }
    __syncthreads();
    if (t == 0) {
        const double    losses = (sl[0] + sl[1]) + (sl[2] + sl[3]);
        const long long counts = sc[0] + sc[1] + sc[2] + sc[3];
        out[0] = (float)((counts > 0) ? losses / (double)counts : losses);
    }
}

extern "C" void kernel_launch(void* const* d_in, const int* in_sizes, int n_in,
                              void* d_out, int out_size, void* d_ws, size_t ws_size,
                              hipStream_t stream) {
    const float* H = (const float*)d_in[0];  // hash_features [256][64] fp32
    const float* L = (const float*)d_in[1];  // labels        [256][14] fp32
    float* out = (float*)d_out;              // scalar fp32

    double*    loss_i = (double*)d_ws;            // 256 doubles
    long long* cnt_i  = (long long*)(loss_i + N); // 256 int64

    osml_anchor<<<N, TPB, 0, stream>>>(H, L, loss_i, cnt_i);
    osml_final<<<1, N, 0, stream>>>(loss_i, cnt_i, out);
}

// Round 8
// 25.944 us; speedup vs baseline: 1.6355x; 1.5513x over previous
//
#include <hip/hip_runtime.h>

#define N    256
#define NH   64
#define NC   14
#define FCH  4            // fallback k-chunks (grid.y of osml_scan)
#define KPC  (N / FCH)    // 64 k's per fallback chunk
#define MARGIN 1e-2f      // screen slack >> f32 encoding error (~2e-6)

// ---------------------------------------------------------------------------
// Kernel 1: one block per anchor i, 256 threads (thread j owns column j).
//  - fp64 dot ds_ij (computed ONCE per (i,j) — no redundancy)
//  - dg_ij exact int; LDS histogram + per-bin f32 min/max of ds (atomicMin/Max
//    on positive-float bits: monotone, order-free, exact)
//  - closed form from histogram (exact integers):
//      Z_i   = sum_d h[d] * (2^d * cntlt[d] - sumlt[d])
//      cnt_i = sum_d h[d] * (h[d-1] + h[d-2])
//      U_i   = sum_d h[d] * u(d),  u(d) = 2^(d-1) h[d-1] + 3*2^(d-2) h[d-2]
//  - no-clip screen: kept pairs only pair bins (d+1,d),(d+2,d); if
//      min ds over bins{d+1,d+2}  >=  max ds over bin d  - 5 + margin  (all d)
//    then relu never clips and num_i = sum_j ds_ij*(u_j - v_j) + 5*U_i exactly.
//    Otherwise flag the anchor for the direct-scan fallback.
// ---------------------------------------------------------------------------
__global__ __launch_bounds__(256) void osml_closed(
    const float* __restrict__ H,      // hash_features [N][NH]
    const float* __restrict__ L,      // labels        [N][NC]
    double*    __restrict__ loss_i,   // [N] closed-form loss (valid if !flag)
    long long* __restrict__ z_i,      // [N] exact Z (valid always)
    long long* __restrict__ cnt_i,    // [N] exact keep-count (valid always)
    int*       __restrict__ flag_i)   // [N] 1 -> needs direct scan
{
    const int i = blockIdx.x, j = threadIdx.x;

    __shared__ float     Hi[NH];
    __shared__ float     Li[NC];
    __shared__ int       hist[18];    // bins 0..14 used; padded zeros to 17
    __shared__ unsigned  bmin[16], bmax[16];
    __shared__ double    w_num[4];
    __shared__ long long sU, sZ, sC;
    __shared__ int       sflag;

    if (j < NH)                     Hi[j]        = H[i*NH + j];
    else if (j < NH + NC)           Li[j - NH]   = L[i*NC + (j - NH)];
    else if (j >= 96  && j < 114)   hist[j - 96] = 0;
    else if (j >= 128 && j < 144)   bmin[j-128]  = 0x7f800000u;  // +inf bits
    else if (j >= 144 && j < 160)   bmax[j-144]  = 0u;
    __syncthreads();

    // fp64 dot: ds_ij = 0.5*(NH - <H_i, H_j>)
    const float4* Hj4 = (const float4*)(H + j*NH);
    double a0=0.0, a1=0.0, a2=0.0, a3=0.0;
    #pragma unroll
    for (int q = 0; q < NH/4; ++q) {
        float4 v = Hj4[q];
        a0 += (double)Hi[4*q+0] * (double)v.x;
        a1 += (double)Hi[4*q+1] * (double)v.y;
        a2 += (double)Hi[4*q+2] * (double)v.z;
        a3 += (double)Hi[4*q+3] * (double)v.w;
    }
    const double dsj = 0.5 * ((double)NH - ((a0+a1)+(a2+a3)));

    // dg_ij: 0/1 dot, <=14 terms -> exact in fp32; diagonal zeroed
    float dsum = 0.f;
    #pragma unroll
    for (int c = 0; c < NC; ++c) dsum += Li[c] * L[j*NC + c];
    int dj = (int)(dsum + 0.5f);
    if (j == i) dj = 0;

    atomicAdd(&hist[dj], 1);                       // exact, order-free
    const unsigned fb = __float_as_uint((float)dsj); // ds>=0 -> monotone bits
    atomicMin(&bmin[dj], fb);
    atomicMax(&bmax[dj], fb);
    __syncthreads();

    if (j == 0) {
        int c = 0, s = 0, fl = 0;
        long long U = 0, Z = 0, C = 0;
        #pragma unroll
        for (int d = 0; d < 16; ++d) {
            long long u = 0, cp = 0;
            if (d >= 1) { u += (long long)(1 << (d-1)) * hist[d-1]; cp += hist[d-1]; }
            if (d >= 2) { u += 3LL * (1 << (d-2)) * hist[d-2];      cp += hist[d-2]; }
            U += (long long)hist[d] * u;
            C += (long long)hist[d] * cp;
            Z += (long long)hist[d] * ((long long)(1 << d) * c - s);
            if (hist[d] > 0) {                      // bin d as k-side
                const float mx = __uint_as_float(bmax[d]);
                float mn = 1e30f;                   // j-side: bins d+1, d+2
                if (d+1 < 16 && hist[d+1] > 0) mn = fminf(mn, __uint_as_float(bmin[d+1]));
                if (d+2 < 16 && hist[d+2] > 0) mn = fminf(mn, __uint_as_float(bmin[d+2]));
                if (mn < mx - 5.0f + MARGIN) fl = 1;
            }
            c += hist[d]; s += hist[d] << d;
        }
        sU = U; sZ = Z; sC = C; sflag = fl;
    }
    __syncthreads();

    // per-j closed-form weight: u_j (j-side) - v_j (k-side)
    long long u_j = 0;
    if (dj >= 1) u_j += (long long)(1 << (dj-1)) * hist[dj-1];
    if (dj >= 2) u_j += 3LL * (1 << (dj-2)) * hist[dj-2];
    const long long v_j = (long long)(1 << dj) * (hist[dj+1] + 3*hist[dj+2]);
    double val = dsj * (double)(u_j - v_j);

    #pragma unroll
    for (int off = 32; off > 0; off >>= 1)
        val += __shfl_down(val, off, 64);
    if ((j & 63) == 0) w_num[j >> 6] = val;
    __syncthreads();
    if (j == 0) {
        const double num = ((w_num[0]+w_num[1])+(w_num[2]+w_num[3])) + 5.0*(double)sU;
        loss_i[i] = (sZ > 0) ? num / (double)sZ : 0.0;
        z_i[i]    = sZ;
        cnt_i[i]  = sC;
        flag_i[i] = sflag;
    }
}

// ---------------------------------------------------------------------------
// Kernel 2: direct-scan fallback, only for flagged anchors (exact relu path).
// grid (N, FCH); unflagged blocks exit immediately. Inner body identical to
// the round-4/7 validated scan. Writes per-(i,ch) fp64 partial numerators.
// ---------------------------------------------------------------------------
__global__ __launch_bounds__(256) void osml_scan(
    const float* __restrict__ H,
    const float* __restrict__ L,
    const int*   __restrict__ flag_i,
    double*      __restrict__ p_num)   // [N*FCH]
{
    const int i = blockIdx.x;
    if (flag_i[i] == 0) return;        // uniform per block; no barrier crossed
    const int ch = blockIdx.y, j = threadIdx.x;

    __shared__ float  Hi[NH];
    __shared__ float  Li[NC];
    __shared__ double ds[N];
    __shared__ int    dg[N];
    __shared__ double w_num[4];

    if (j < NH) Hi[j] = H[i*NH + j];
    else if (j < NH + NC) Li[j - NH] = L[i*NC + (j - NH)];
    __syncthreads();

    const float4* Hj4 = (const float4*)(H + j*NH);
    double a0=0.0, a1=0.0, a2=0.0, a3=0.0;
    #pragma unroll
    for (int q = 0; q < NH/4; ++q) {
        float4 v = Hj4[q];
        a0 += (double)Hi[4*q+0] * (double)v.x;
        a1 += (double)Hi[4*q+1] * (double)v.y;
        a2 += (double)Hi[4*q+2] * (double)v.z;
        a3 += (double)Hi[4*q+3] * (double)v.w;
    }
    ds[j] = 0.5 * ((double)NH - ((a0+a1)+(a2+a3)));

    float dsum = 0.f;
    #pragma unroll
    for (int c = 0; c < NC; ++c) dsum += Li[c] * L[j*NC + c];
    int d = (int)(dsum + 0.5f);
    if (j == i) d = 0;
    dg[j] = d;
    __syncthreads();

    const int    dj   = dg[j];
    const int    g2j  = 1 << dj;
    const double dsj5 = ds[j] + 5.0;
    const double r1   = (double)(g2j >> 1);        // dk == dj-1
    const double r2   = (double)(3 * (g2j >> 2));  // dk == dj-2

    double n0 = 0.0, n1 = 0.0;
    const int k0 = ch * KPC;
#define OSML_BODY(O, ACC) {                                        \
        const int    dd = dj - dg[k0 + kk + (O)];                  \
        double       w  = (dd == 1) ? r1 : ((dd == 2) ? r2 : 0.0); \
        const double tt = dsj5 - ds[k0 + kk + (O)];                \
        w = (tt > 0.0) ? w : 0.0;                                  \
        ACC = fma(w, tt, ACC); }
    #pragma unroll
    for (int kk = 0; kk < KPC; kk += 2) {
        OSML_BODY(0, n0)
        OSML_BODY(1, n1)
    }
#undef OSML_BODY
    double num = n0 + n1;

    #pragma unroll
    for (int off = 32; off > 0; off >>= 1)
        num += __shfl_down(num, off, 64);
    if ((j & 63) == 0) w_num[j >> 6] = num;
    __syncthreads();
    if (j == 0)
        p_num[i*FCH + ch] = ((w_num[0]+w_num[1])+(w_num[2]+w_num[3]));
}

// ---------------------------------------------------------------------------
// Kernel 3: pick closed-form or fallback loss per anchor, reduce, write scalar.
// ---------------------------------------------------------------------------
__global__ __launch_bounds__(256) void osml_final(
    const double*    __restrict__ loss_i,
    const long long* __restrict__ z_i,
    const long long* __restrict__ cnt_i,
    const int*       __restrict__ flag_i,
    const double*    __restrict__ p_num,
    float*           __restrict__ out)
{
    const int t = threadIdx.x;
    double l;
    long long c = cnt_i[t];
    if (flag_i[t]) {
        const double nm = ((p_num[t*FCH+0] + p_num[t*FCH+1])
                         + (p_num[t*FCH+2] + p_num[t*FCH+3]));
        const long long Z = z_i[t];
        l = (Z > 0) ? nm / (double)Z : 0.0;
    } else {
        l = loss_i[t];
    }
    #pragma unroll
    for (int off = 32; off > 0; off >>= 1) {
        l += __shfl_down(l, off, 64);
        c += __shfl_down(c, off, 64);
    }
    __shared__ double    sl[4];
    __shared__ long long sc[4];
    if ((t & 63) == 0) { sl[t >> 6] = l; sc[t >> 6] = c; }
    __syncthreads();
    if (t == 0) {
        const double    losses = (sl[0]+sl[1]) + (sl[2]+sl[3]);
        const long long counts = sc[0]+sc[1]+sc[2]+sc[3];
        out[0] = (float)((counts > 0) ? losses / (double)counts : losses);
    }
}

extern "C" void kernel_launch(void* const* d_in, const int* in_sizes, int n_in,
                              void* d_out, int out_size, void* d_ws, size_t ws_size,
                              hipStream_t stream) {
    const float* H = (const float*)d_in[0];  // hash_features [256][64] fp32
    const float* L = (const float*)d_in[1];  // labels        [256][14] fp32
    float* out = (float*)d_out;              // scalar fp32

    double*    loss  = (double*)d_ws;              // 256 * 8
    long long* z     = (long long*)(loss + N);     // 256 * 8
    long long* cnt   = (long long*)(z + N);        // 256 * 8
    int*       flag  = (int*)(cnt + N);            // 256 * 4
    double*    p_num = (double*)(flag + N);        // 256*FCH * 8  (8B-aligned)

    osml_closed<<<N, 256, 0, stream>>>(H, L, loss, z, cnt, flag);
    osml_scan<<<dim3(N, FCH), 256, 0, stream>>>(H, L, flag, p_num);
    osml_final<<<1, 256, 0, stream>>>(loss, z, cnt, flag, p_num, out);
}

// Round 9
// 21.471 us; speedup vs baseline: 1.9762x; 1.2083x over previous
//
#include <hip/hip_runtime.h>

#define N    256
#define NH   64
#define NC   14
#define MARGIN 1e-2f      // no-clip screen slack >> f32 encoding error (~2e-6)

// ---------------------------------------------------------------------------
// Kernel A: one block per anchor i, 256 threads (thread j owns column j).
// Closed-form numerator from the 15-bin label-distance histogram (exact
// integer weights; valid when relu never clips), with an exact conservative
// per-bin min/max screen; if the screen flags possible clipping, THIS block
// falls back inline to the direct 256-iter scan (R3-validated body) using the
// ds/dg rows already in LDS. Z and keep-count are always closed-form (exact,
// relu-independent). All reductions fixed-order -> deterministic.
// ---------------------------------------------------------------------------
__global__ __launch_bounds__(256) void osml_main(
    const float* __restrict__ H,      // hash_features [N][NH]
    const float* __restrict__ L,      // labels        [N][NC]
    double*    __restrict__ loss_i,   // [N]
    long long* __restrict__ cnt_i)    // [N]
{
    const int i = blockIdx.x, j = threadIdx.x;

    __shared__ float     Hi[NH];
    __shared__ float     Li[NC];
    __shared__ double    ds[N];       // dist_sim row i (fp64)
    __shared__ int       dg[N];       // dist_gt row i (exact int)
    __shared__ int       hist[18];    // bins 0..14 used; 15..17 stay zero
    __shared__ unsigned  bmin[16], bmax[16];
    __shared__ double    w_num[4];
    __shared__ long long sU, sZ, sC;
    __shared__ int       sflag;

    if (j < NH)                     Hi[j]        = H[i*NH + j];
    else if (j < NH + NC)           Li[j - NH]   = L[i*NC + (j - NH)];
    else if (j >= 96  && j < 114)   hist[j - 96] = 0;
    else if (j >= 128 && j < 144)   bmin[j-128]  = 0x7f800000u;  // +inf bits
    else if (j >= 144 && j < 160)   bmax[j-144]  = 0u;
    __syncthreads();

    // fp64 dot: ds_ij = 0.5*(NH - <H_i, H_j>)  (computed once per (i,j))
    const float4* Hj4 = (const float4*)(H + j*NH);
    double a0=0.0, a1=0.0, a2=0.0, a3=0.0;
    #pragma unroll
    for (int q = 0; q < NH/4; ++q) {
        float4 v = Hj4[q];
        a0 += (double)Hi[4*q+0] * (double)v.x;
        a1 += (double)Hi[4*q+1] * (double)v.y;
        a2 += (double)Hi[4*q+2] * (double)v.z;
        a3 += (double)Hi[4*q+3] * (double)v.w;
    }
    const double dsj = 0.5 * ((double)NH - ((a0+a1)+(a2+a3)));
    ds[j] = dsj;

    // dg_ij: 0/1 dot, <=14 terms -> exact in fp32; diagonal zeroed
    float dsum = 0.f;
    #pragma unroll
    for (int c = 0; c < NC; ++c) dsum += Li[c] * L[j*NC + c];
    int dj = (int)(dsum + 0.5f);
    if (j == i) dj = 0;
    dg[j] = dj;

    atomicAdd(&hist[dj], 1);                         // exact, order-free
    const unsigned fb = __float_as_uint((float)dsj); // ds>=0 -> monotone bits
    atomicMin(&bmin[dj], fb);
    atomicMax(&bmax[dj], fb);
    __syncthreads();

    if (j == 0) {
        int c = 0, s = 0, fl = 0;
        long long U = 0, Z = 0, C = 0;
        #pragma unroll
        for (int d = 0; d < 16; ++d) {
            long long u = 0, cp = 0;
            if (d >= 1) { u += (long long)(1 << (d-1)) * hist[d-1]; cp += hist[d-1]; }
            if (d >= 2) { u += 3LL * (1 << (d-2)) * hist[d-2];      cp += hist[d-2]; }
            U += (long long)hist[d] * u;
            C += (long long)hist[d] * cp;
            Z += (long long)hist[d] * ((long long)(1 << d) * c - s);
            if (hist[d] > 0) {                       // bin d as k-side
                const float mx = __uint_as_float(bmax[d]);
                float mn = 1e30f;                    // j-side: bins d+1, d+2
                if (d+1 < 16 && hist[d+1] > 0) mn = fminf(mn, __uint_as_float(bmin[d+1]));
                if (d+2 < 16 && hist[d+2] > 0) mn = fminf(mn, __uint_as_float(bmin[d+2]));
                if (mn < mx - 5.0f + MARGIN) fl = 1;
            }
            c += hist[d]; s += hist[d] << d;
        }
        sU = U; sZ = Z; sC = C; sflag = fl;
    }
    __syncthreads();

    double num;
    if (!sflag) {
        // closed form: num_i = sum_j ds_ij*(u_j - v_j) + 5*U  (exact weights)
        long long u_j = 0;
        if (dj >= 1) u_j += (long long)(1 << (dj-1)) * hist[dj-1];
        if (dj >= 2) u_j += 3LL * (1 << (dj-2)) * hist[dj-2];
        const long long v_j = (long long)(1 << dj) * (hist[dj+1] + 3*hist[dj+2]);
        num = dsj * (double)(u_j - v_j);
    } else {
        // inline exact fallback (R3-validated scan body); block-uniform branch
        const int    g2j  = 1 << dj;
        const double dsj5 = dsj + 5.0;
        const double r1   = (double)(g2j >> 1);        // dk == dj-1
        const double r2   = (double)(3 * (g2j >> 2));  // dk == dj-2
        double n0 = 0.0, n1 = 0.0;
#define OSML_BODY(O, ACC) {                                        \
            const int    dd = dj - dg[kk + (O)];                   \
            double       w  = (dd == 1) ? r1 : ((dd == 2) ? r2 : 0.0); \
            const double tt = dsj5 - ds[kk + (O)];                 \
            w = (tt > 0.0) ? w : 0.0;                              \
            ACC = fma(w, tt, ACC); }
        #pragma unroll 8
        for (int kk = 0; kk < N; kk += 2) {
            OSML_BODY(0, n0)
            OSML_BODY(1, n1)
        }
#undef OSML_BODY
        num = n0 + n1;
    }

    // fixed-order wave reduce, then 4 wave-partials summed sequentially
    #pragma unroll
    for (int off = 32; off > 0; off >>= 1)
        num += __shfl_down(num, off, 64);
    if ((j & 63) == 0) w_num[j >> 6] = num;
    __syncthreads();
    if (j == 0) {
        double total = ((w_num[0]+w_num[1])+(w_num[2]+w_num[3]));
        if (!sflag) total += 5.0 * (double)sU;       // constant term, closed path
        loss_i[i] = (sZ > 0) ? total / (double)sZ : 0.0;
        cnt_i[i]  = sC;
    }
}

// ---------------------------------------------------------------------------
// Kernel B: single block, deterministic reduction over the 256 anchors.
// ---------------------------------------------------------------------------
__global__ __launch_bounds__(256) void osml_final(
    const double*    __restrict__ loss_i,
    const long long* __restrict__ cnt_i,
    float*           __restrict__ out)
{
    const int t = threadIdx.x;
    double    l = loss_i[t];
    long long c = cnt_i[t];
    #pragma unroll
    for (int off = 32; off > 0; off >>= 1) {
        l += __shfl_down(l, off, 64);
        c += __shfl_down(c, off, 64);
    }
    __shared__ double    sl[4];
    __shared__ long long sc[4];
    if ((t & 63) == 0) { sl[t >> 6] = l; sc[t >> 6] = c; }
    __syncthreads();
    if (t == 0) {
        const double    losses = (sl[0]+sl[1]) + (sl[2]+sl[3]);
        const long long counts = sc[0]+sc[1]+sc[2]+sc[3];
        out[0] = (float)((counts > 0) ? losses / (double)counts : losses);
    }
}

extern "C" void kernel_launch(void* const* d_in, const int* in_sizes, int n_in,
                              void* d_out, int out_size, void* d_ws, size_t ws_size,
                              hipStream_t stream) {
    const float* H = (const float*)d_in[0];  // hash_features [256][64] fp32
    const float* L = (const float*)d_in[1];  // labels        [256][14] fp32
    float* out = (float*)d_out;              // scalar fp32

    double*    loss = (double*)d_ws;             // 256 * 8 B
    long long* cnt  = (long long*)(loss + N);    // 256 * 8 B

    osml_main<<<N, 256, 0, stream>>>(H, L, loss, cnt);
    osml_final<<<1, 256, 0, stream>>>(loss, cnt, out);
}